// Round 1
// baseline (2916.700 us; speedup 1.0000x reference)
//
#include <hip/hip_runtime.h>

#define HIDDEN 128

// ---------------------------------------------------------------------------
// Scatter-add: agg[dst[e]] += x[src[e]]  (row width 128 fp32)
// 32 threads per edge, each handles one float4 chunk (4 atomicAdds).
// ---------------------------------------------------------------------------
__global__ __launch_bounds__(256) void scatter_add_kernel(
    const float* __restrict__ x, const int* __restrict__ src,
    const int* __restrict__ dst, float* __restrict__ agg, int E) {
  int tid = blockIdx.x * blockDim.x + threadIdx.x;
  int e = tid >> 5;
  if (e >= E) return;
  int q = tid & 31;
  int s = src[e];
  int d = dst[e];
  float4 v = ((const float4*)(x + (size_t)s * HIDDEN))[q];
  float* out = agg + (size_t)d * HIDDEN + q * 4;
  atomicAdd(out + 0, v.x);
  atomicAdd(out + 1, v.y);
  atomicAdd(out + 2, v.z);
  atomicAdd(out + 3, v.w);
}

// ---------------------------------------------------------------------------
// C[M,128] = act(A[M,128] @ W[128,128] + bias)   (act = relu if applyRelu)
// Block: 256 threads computes a 64x64 tile; micro-tile 4x4 per thread.
// K split into two 64-chunks staged in LDS (xs, ws), float4 loads.
// ---------------------------------------------------------------------------
__global__ __launch_bounds__(256) void gemm_bias_relu_kernel(
    const float* __restrict__ A, const float* __restrict__ W,
    const float* __restrict__ bias, float* __restrict__ C, int M,
    int applyRelu) {
  __shared__ float xs[64][68];  // [m][k]  pad 68 -> row shift 4 banks
  __shared__ float ws[64][68];  // [k][n]
  const int t = threadIdx.x;
  const int tx = t & 15;   // col group (n = tx*4)
  const int ty = t >> 4;   // row group (m = ty*4)
  const int mBase = blockIdx.x * 64;
  const int nBase = blockIdx.y * 64;

  float acc[4][4];
#pragma unroll
  for (int i = 0; i < 4; ++i)
#pragma unroll
    for (int j = 0; j < 4; ++j) acc[i][j] = 0.f;

  for (int kt = 0; kt < HIDDEN; kt += 64) {
    // cooperative stage: 64x64 of A and of W, 4 float4 per thread each
#pragma unroll
    for (int i = 0; i < 4; ++i) {
      int idx = t + i * 256;
      int r = idx >> 4;          // 0..63
      int c = (idx & 15) * 4;    // 0..60
      int gm = mBase + r;
      float4 xv = make_float4(0.f, 0.f, 0.f, 0.f);
      if (gm < M) xv = *(const float4*)(A + (size_t)gm * HIDDEN + kt + c);
      *(float4*)&xs[r][c] = xv;
      float4 wv = *(const float4*)(W + (size_t)(kt + r) * HIDDEN + nBase + c);
      *(float4*)&ws[r][c] = wv;
    }
    __syncthreads();

#pragma unroll
    for (int k = 0; k < 64; k += 4) {
      float aa[4][4];  // [i][kk]
      float ww[4][4];  // [kk][j]
#pragma unroll
      for (int i = 0; i < 4; ++i) {
        float4 a4 = *(const float4*)&xs[ty * 4 + i][k];
        aa[i][0] = a4.x; aa[i][1] = a4.y; aa[i][2] = a4.z; aa[i][3] = a4.w;
      }
#pragma unroll
      for (int kk = 0; kk < 4; ++kk) {
        float4 w4 = *(const float4*)&ws[k + kk][tx * 4];
        ww[kk][0] = w4.x; ww[kk][1] = w4.y; ww[kk][2] = w4.z; ww[kk][3] = w4.w;
      }
#pragma unroll
      for (int i = 0; i < 4; ++i)
#pragma unroll
        for (int kk = 0; kk < 4; ++kk)
#pragma unroll
          for (int j = 0; j < 4; ++j) acc[i][j] += aa[i][kk] * ww[kk][j];
    }
    __syncthreads();
  }

  float4 bv = *(const float4*)(bias + nBase + tx * 4);
#pragma unroll
  for (int i = 0; i < 4; ++i) {
    int gm = mBase + ty * 4 + i;
    if (gm >= M) continue;
    float4 o;
    o.x = acc[i][0] + bv.x;
    o.y = acc[i][1] + bv.y;
    o.z = acc[i][2] + bv.z;
    o.w = acc[i][3] + bv.w;
    if (applyRelu) {
      o.x = fmaxf(o.x, 0.f);
      o.y = fmaxf(o.y, 0.f);
      o.z = fmaxf(o.z, 0.f);
      o.w = fmaxf(o.w, 0.f);
    }
    *(float4*)(C + (size_t)gm * HIDDEN + nBase + tx * 4) = o;
  }
}

// ---------------------------------------------------------------------------
// out[m] = dot(h[m,:], Wr) + br   — one 64-lane wave per row, shfl reduce
// ---------------------------------------------------------------------------
__global__ __launch_bounds__(256) void readout_kernel(
    const float* __restrict__ h, const float* __restrict__ Wr,
    const float* __restrict__ br, float* __restrict__ out, int M) {
  int wid = (int)((blockIdx.x * blockDim.x + threadIdx.x) >> 6);
  int lane = threadIdx.x & 63;
  if (wid >= M) return;
  float2 hv = *(const float2*)(h + (size_t)wid * HIDDEN + lane * 2);
  float2 wv = *(const float2*)(Wr + lane * 2);
  float p = hv.x * wv.x + hv.y * wv.y;
#pragma unroll
  for (int off = 32; off; off >>= 1) p += __shfl_down(p, off);
  if (lane == 0) out[wid] = p + br[0];
}

extern "C" void kernel_launch(void* const* d_in, const int* in_sizes, int n_in,
                              void* d_out, int out_size, void* d_ws,
                              size_t ws_size, hipStream_t stream) {
  const float* x = (const float*)d_in[0];
  const int* ei = (const int*)d_in[1];
  const float* W1_0 = (const float*)d_in[2];
  const float* b1_0 = (const float*)d_in[3];
  const float* W2_0 = (const float*)d_in[4];
  const float* b2_0 = (const float*)d_in[5];
  const float* W1_1 = (const float*)d_in[6];
  const float* b1_1 = (const float*)d_in[7];
  const float* W2_1 = (const float*)d_in[8];
  const float* b2_1 = (const float*)d_in[9];
  const float* Wr = (const float*)d_in[10];
  const float* br = (const float*)d_in[11];

  const int M = in_sizes[0] / HIDDEN;  // 50000 nodes
  const int E = in_sizes[1] / 2;       // 800000 edges
  const int* src = ei;
  const int* dst = ei + E;

  float* A = (float*)d_ws;
  float* B = A + (size_t)M * HIDDEN;
  const size_t rowBytes = (size_t)M * HIDDEN * sizeof(float);

  dim3 gemmGrid((M + 63) / 64, HIDDEN / 64);
  const int scatterBlocks = (E * 32 + 255) / 256;
  float* out = (float*)d_out;

  // ---- layer 0: h = relu( relu((x+agg(x)) @ W1_0 + b1_0) @ W2_0 + b2_0 )
  hipMemcpyAsync(A, x, rowBytes, hipMemcpyDeviceToDevice, stream);
  scatter_add_kernel<<<scatterBlocks, 256, 0, stream>>>(x, src, dst, A, E);
  gemm_bias_relu_kernel<<<gemmGrid, 256, 0, stream>>>(A, W1_0, b1_0, B, M, 1);
  gemm_bias_relu_kernel<<<gemmGrid, 256, 0, stream>>>(B, W2_0, b2_0, A, M, 1);

  // ---- layer 1
  hipMemcpyAsync(B, A, rowBytes, hipMemcpyDeviceToDevice, stream);
  scatter_add_kernel<<<scatterBlocks, 256, 0, stream>>>(A, src, dst, B, E);
  gemm_bias_relu_kernel<<<gemmGrid, 256, 0, stream>>>(B, W1_1, b1_1, A, M, 1);
  gemm_bias_relu_kernel<<<gemmGrid, 256, 0, stream>>>(A, W2_1, b2_1, B, M, 1);

  // ---- readout
  readout_kernel<<<(M + 3) / 4, 256, 0, stream>>>(B, Wr, br, out, M);
}

// Round 2
// 498.014 us; speedup vs baseline: 5.8567x; 5.8567x over previous
//
#include <hip/hip_runtime.h>

#define HIDDEN 128

// ---------------------------------------------------------------------------
// CSR build step 1: degree histogram over dst
// ---------------------------------------------------------------------------
__global__ __launch_bounds__(256) void hist_kernel(const int* __restrict__ dst,
                                                   int* __restrict__ deg, int E) {
  int e = blockIdx.x * blockDim.x + threadIdx.x;
  if (e < E) atomicAdd(&deg[dst[e]], 1);
}

// ---------------------------------------------------------------------------
// CSR build step 2: exclusive prefix sum deg[0..N) -> rowptr[0..N]
// Single block, 256 threads, each owns a contiguous chunk.
// ---------------------------------------------------------------------------
__global__ __launch_bounds__(256) void scan_kernel(const int* __restrict__ deg,
                                                   int* __restrict__ rowptr, int N) {
  __shared__ int sums[256];
  const int t = threadIdx.x;
  const int chunk = (N + 255) / 256;
  const int begin = t * chunk;
  const int end = min(begin + chunk, N);
  int s = 0;
  for (int i = begin; i < end; ++i) s += deg[i];
  sums[t] = s;
  __syncthreads();
  // Hillis-Steele inclusive scan over the 256 partial sums
  for (int off = 1; off < 256; off <<= 1) {
    int n = (t >= off) ? sums[t - off] : 0;
    __syncthreads();
    sums[t] += n;
    __syncthreads();
  }
  int run = sums[t] - s;  // exclusive prefix for this chunk
  for (int i = begin; i < end; ++i) {
    rowptr[i] = run;
    run += deg[i];
  }
  if (end == N) rowptr[N] = run;  // total (same value from any qualifying thread)
}

// ---------------------------------------------------------------------------
// CSR build step 3: fill column (src) lists using per-node cursors
// ---------------------------------------------------------------------------
__global__ __launch_bounds__(256) void fill_kernel(const int* __restrict__ src,
                                                   const int* __restrict__ dst,
                                                   int* __restrict__ cursor,
                                                   int* __restrict__ col, int E) {
  int e = blockIdx.x * blockDim.x + threadIdx.x;
  if (e >= E) return;
  int pos = atomicAdd(&cursor[dst[e]], 1);
  col[pos] = src[e];
}

// ---------------------------------------------------------------------------
// Aggregation as GATHER: out[i,:] = x[i,:] + sum_{e} x[col[e],:]
// One 64-lane wave per node; each lane owns a float2 column slice.
// 4-way edge unroll for load-latency overlap.
// ---------------------------------------------------------------------------
__global__ __launch_bounds__(256) void aggregate_kernel(
    const float* __restrict__ x, const int* __restrict__ rowptr,
    const int* __restrict__ col, float* __restrict__ out, int N) {
  int wid = (int)((blockIdx.x * (size_t)blockDim.x + threadIdx.x) >> 6);
  int lane = threadIdx.x & 63;
  if (wid >= N) return;
  const int s = rowptr[wid];
  const int e = rowptr[wid + 1];
  const int off = lane * 2;
  float2 acc = *(const float2*)(x + (size_t)wid * HIDDEN + off);
  int i = s;
  for (; i + 3 < e; i += 4) {
    int c0 = col[i], c1 = col[i + 1], c2 = col[i + 2], c3 = col[i + 3];
    float2 v0 = *(const float2*)(x + (size_t)c0 * HIDDEN + off);
    float2 v1 = *(const float2*)(x + (size_t)c1 * HIDDEN + off);
    float2 v2 = *(const float2*)(x + (size_t)c2 * HIDDEN + off);
    float2 v3 = *(const float2*)(x + (size_t)c3 * HIDDEN + off);
    acc.x += v0.x + v1.x + v2.x + v3.x;
    acc.y += v0.y + v1.y + v2.y + v3.y;
  }
  for (; i < e; ++i) {
    int c = col[i];
    float2 v = *(const float2*)(x + (size_t)c * HIDDEN + off);
    acc.x += v.x;
    acc.y += v.y;
  }
  *(float2*)(out + (size_t)wid * HIDDEN + off) = acc;
}

// ---------------------------------------------------------------------------
// C[M,128] = act(A[M,128] @ W[128,128] + bias)   (act = relu if applyRelu)
// Block: 256 threads computes a 64x64 tile; micro-tile 4x4 per thread.
// ---------------------------------------------------------------------------
__global__ __launch_bounds__(256) void gemm_bias_relu_kernel(
    const float* __restrict__ A, const float* __restrict__ W,
    const float* __restrict__ bias, float* __restrict__ C, int M,
    int applyRelu) {
  __shared__ float xs[64][68];
  __shared__ float ws[64][68];
  const int t = threadIdx.x;
  const int tx = t & 15;
  const int ty = t >> 4;
  const int mBase = blockIdx.x * 64;
  const int nBase = blockIdx.y * 64;

  float acc[4][4];
#pragma unroll
  for (int i = 0; i < 4; ++i)
#pragma unroll
    for (int j = 0; j < 4; ++j) acc[i][j] = 0.f;

  for (int kt = 0; kt < HIDDEN; kt += 64) {
#pragma unroll
    for (int i = 0; i < 4; ++i) {
      int idx = t + i * 256;
      int r = idx >> 4;
      int c = (idx & 15) * 4;
      int gm = mBase + r;
      float4 xv = make_float4(0.f, 0.f, 0.f, 0.f);
      if (gm < M) xv = *(const float4*)(A + (size_t)gm * HIDDEN + kt + c);
      *(float4*)&xs[r][c] = xv;
      float4 wv = *(const float4*)(W + (size_t)(kt + r) * HIDDEN + nBase + c);
      *(float4*)&ws[r][c] = wv;
    }
    __syncthreads();

#pragma unroll
    for (int k = 0; k < 64; k += 4) {
      float aa[4][4];
      float ww[4][4];
#pragma unroll
      for (int i = 0; i < 4; ++i) {
        float4 a4 = *(const float4*)&xs[ty * 4 + i][k];
        aa[i][0] = a4.x; aa[i][1] = a4.y; aa[i][2] = a4.z; aa[i][3] = a4.w;
      }
#pragma unroll
      for (int kk = 0; kk < 4; ++kk) {
        float4 w4 = *(const float4*)&ws[k + kk][tx * 4];
        ww[kk][0] = w4.x; ww[kk][1] = w4.y; ww[kk][2] = w4.z; ww[kk][3] = w4.w;
      }
#pragma unroll
      for (int i = 0; i < 4; ++i)
#pragma unroll
        for (int kk = 0; kk < 4; ++kk)
#pragma unroll
          for (int j = 0; j < 4; ++j) acc[i][j] += aa[i][kk] * ww[kk][j];
    }
    __syncthreads();
  }

  float4 bv = *(const float4*)(bias + nBase + tx * 4);
#pragma unroll
  for (int i = 0; i < 4; ++i) {
    int gm = mBase + ty * 4 + i;
    if (gm >= M) continue;
    float4 o;
    o.x = acc[i][0] + bv.x;
    o.y = acc[i][1] + bv.y;
    o.z = acc[i][2] + bv.z;
    o.w = acc[i][3] + bv.w;
    if (applyRelu) {
      o.x = fmaxf(o.x, 0.f);
      o.y = fmaxf(o.y, 0.f);
      o.z = fmaxf(o.z, 0.f);
      o.w = fmaxf(o.w, 0.f);
    }
    *(float4*)(C + (size_t)gm * HIDDEN + nBase + tx * 4) = o;
  }
}

// ---------------------------------------------------------------------------
// out[m] = dot(h[m,:], Wr) + br   — one 64-lane wave per row, shfl reduce
// ---------------------------------------------------------------------------
__global__ __launch_bounds__(256) void readout_kernel(
    const float* __restrict__ h, const float* __restrict__ Wr,
    const float* __restrict__ br, float* __restrict__ out, int M) {
  int wid = (int)((blockIdx.x * blockDim.x + threadIdx.x) >> 6);
  int lane = threadIdx.x & 63;
  if (wid >= M) return;
  float2 hv = *(const float2*)(h + (size_t)wid * HIDDEN + lane * 2);
  float2 wv = *(const float2*)(Wr + lane * 2);
  float p = hv.x * wv.x + hv.y * wv.y;
#pragma unroll
  for (int off = 32; off; off >>= 1) p += __shfl_down(p, off);
  if (lane == 0) out[wid] = p + br[0];
}

extern "C" void kernel_launch(void* const* d_in, const int* in_sizes, int n_in,
                              void* d_out, int out_size, void* d_ws,
                              size_t ws_size, hipStream_t stream) {
  const float* x = (const float*)d_in[0];
  const int* ei = (const int*)d_in[1];
  const float* W1_0 = (const float*)d_in[2];
  const float* b1_0 = (const float*)d_in[3];
  const float* W2_0 = (const float*)d_in[4];
  const float* b2_0 = (const float*)d_in[5];
  const float* W1_1 = (const float*)d_in[6];
  const float* b1_1 = (const float*)d_in[7];
  const float* W2_1 = (const float*)d_in[8];
  const float* b2_1 = (const float*)d_in[9];
  const float* Wr = (const float*)d_in[10];
  const float* br = (const float*)d_in[11];

  const int M = in_sizes[0] / HIDDEN;  // 50000 nodes
  const int E = in_sizes[1] / 2;       // 800000 edges
  const int* src = ei;
  const int* dst = ei + E;

  // workspace layout
  float* A = (float*)d_ws;                   // [M,128]
  float* B = A + (size_t)M * HIDDEN;         // [M,128]
  int* deg = (int*)(B + (size_t)M * HIDDEN); // [M]
  int* rowptr = deg + M;                     // [M+1]
  int* cursor = rowptr + M + 1;              // [M]
  int* col = cursor + M;                     // [E]

  dim3 gemmGrid((M + 63) / 64, HIDDEN / 64);
  const int aggBlocks = (int)(((size_t)M * 64 + 255) / 256);
  float* out = (float*)d_out;

  // ---- build CSR (dst -> list of src), reused by both layers
  hipMemsetAsync(deg, 0, (size_t)M * sizeof(int), stream);
  hist_kernel<<<(E + 255) / 256, 256, 0, stream>>>(dst, deg, E);
  scan_kernel<<<1, 256, 0, stream>>>(deg, rowptr, M);
  hipMemcpyAsync(cursor, rowptr, (size_t)M * sizeof(int),
                 hipMemcpyDeviceToDevice, stream);
  fill_kernel<<<(E + 255) / 256, 256, 0, stream>>>(src, dst, cursor, col, E);

  // ---- layer 0
  aggregate_kernel<<<aggBlocks, 256, 0, stream>>>(x, rowptr, col, A, M);
  gemm_bias_relu_kernel<<<gemmGrid, 256, 0, stream>>>(A, W1_0, b1_0, B, M, 1);
  gemm_bias_relu_kernel<<<gemmGrid, 256, 0, stream>>>(B, W2_0, b2_0, A, M, 1);

  // ---- layer 1
  aggregate_kernel<<<aggBlocks, 256, 0, stream>>>(A, rowptr, col, B, M);
  gemm_bias_relu_kernel<<<gemmGrid, 256, 0, stream>>>(B, W1_1, b1_1, A, M, 1);
  gemm_bias_relu_kernel<<<gemmGrid, 256, 0, stream>>>(A, W2_1, b2_1, B, M, 1);

  // ---- readout
  readout_kernel<<<(M + 3) / 4, 256, 0, stream>>>(B, Wr, br, out, M);
}

// Round 3
// 421.088 us; speedup vs baseline: 6.9266x; 1.1827x over previous
//
#include <hip/hip_runtime.h>

#define HIDDEN 128
#define SCAN_CHUNK 256

// ---------------------------------------------------------------------------
// CSR build step 1: degree histogram over dst
// ---------------------------------------------------------------------------
__global__ __launch_bounds__(256) void hist_kernel(const int* __restrict__ dst,
                                                   int* __restrict__ deg, int E) {
  int e = blockIdx.x * blockDim.x + threadIdx.x;
  if (e < E) atomicAdd(&deg[dst[e]], 1);
}

// ---------------------------------------------------------------------------
// CSR scan phase A: per-block chunk sums (chunk = 256 elements, 1/thread)
// ---------------------------------------------------------------------------
__global__ __launch_bounds__(256) void scan_partial_kernel(
    const int* __restrict__ deg, int* __restrict__ partial, int N) {
  __shared__ int red[256];
  const int t = threadIdx.x;
  const int idx = blockIdx.x * SCAN_CHUNK + t;
  red[t] = (idx < N) ? deg[idx] : 0;
  __syncthreads();
#pragma unroll
  for (int off = 128; off; off >>= 1) {
    if (t < off) red[t] += red[t + off];
    __syncthreads();
  }
  if (t == 0) partial[blockIdx.x] = red[0];
}

// ---------------------------------------------------------------------------
// CSR scan phase B: one block scans the (<=256) block partials -> exclusive
// block offsets.
// ---------------------------------------------------------------------------
__global__ __launch_bounds__(256) void scan_offsets_kernel(
    const int* __restrict__ partial, int* __restrict__ blockOff, int nBlocks) {
  __shared__ int sums[256];
  const int t = threadIdx.x;
  const int p = (t < nBlocks) ? partial[t] : 0;
  sums[t] = p;
  __syncthreads();
#pragma unroll
  for (int off = 1; off < 256; off <<= 1) {
    int v = (t >= off) ? sums[t - off] : 0;
    __syncthreads();
    sums[t] += v;
    __syncthreads();
  }
  blockOff[t] = sums[t] - p;  // exclusive
}

// ---------------------------------------------------------------------------
// CSR scan phase C: per-block exclusive scan of its chunk + block offset;
// writes rowptr AND cursor (so no separate d2d copy needed).
// ---------------------------------------------------------------------------
__global__ __launch_bounds__(256) void scan_final_kernel(
    const int* __restrict__ deg, const int* __restrict__ blockOff,
    int* __restrict__ rowptr, int* __restrict__ cursor, int N) {
  __shared__ int sh[256];
  const int t = threadIdx.x;
  const int idx = blockIdx.x * SCAN_CHUNK + t;
  const int v = (idx < N) ? deg[idx] : 0;
  sh[t] = v;
  __syncthreads();
#pragma unroll
  for (int off = 1; off < 256; off <<= 1) {
    int u = (t >= off) ? sh[t - off] : 0;
    __syncthreads();
    sh[t] += u;
    __syncthreads();
  }
  const int excl = sh[t] - v + blockOff[blockIdx.x];
  if (idx < N) {
    rowptr[idx] = excl;
    cursor[idx] = excl;
    if (idx == N - 1) rowptr[N] = excl + v;
  }
}

// ---------------------------------------------------------------------------
// CSR build step 3: fill column (src) lists using per-node cursors
// ---------------------------------------------------------------------------
__global__ __launch_bounds__(256) void fill_kernel(const int* __restrict__ src,
                                                   const int* __restrict__ dst,
                                                   int* __restrict__ cursor,
                                                   int* __restrict__ col, int E) {
  int e = blockIdx.x * blockDim.x + threadIdx.x;
  if (e >= E) return;
  int pos = atomicAdd(&cursor[dst[e]], 1);
  col[pos] = src[e];
}

// ---------------------------------------------------------------------------
// Aggregation as GATHER: out[i,:] = x[i,:] + sum_{e} x[col[e],:]
// One 64-lane wave per node; each lane owns a float2 column slice.
// ---------------------------------------------------------------------------
__global__ __launch_bounds__(256) void aggregate_kernel(
    const float* __restrict__ x, const int* __restrict__ rowptr,
    const int* __restrict__ col, float* __restrict__ out, int N) {
  int wid = (int)((blockIdx.x * (size_t)blockDim.x + threadIdx.x) >> 6);
  int lane = threadIdx.x & 63;
  if (wid >= N) return;
  const int s = rowptr[wid];
  const int e = rowptr[wid + 1];
  const int off = lane * 2;
  float2 acc = *(const float2*)(x + (size_t)wid * HIDDEN + off);
  int i = s;
  for (; i + 3 < e; i += 4) {
    int c0 = col[i], c1 = col[i + 1], c2 = col[i + 2], c3 = col[i + 3];
    float2 v0 = *(const float2*)(x + (size_t)c0 * HIDDEN + off);
    float2 v1 = *(const float2*)(x + (size_t)c1 * HIDDEN + off);
    float2 v2 = *(const float2*)(x + (size_t)c2 * HIDDEN + off);
    float2 v3 = *(const float2*)(x + (size_t)c3 * HIDDEN + off);
    acc.x += v0.x + v1.x + v2.x + v3.x;
    acc.y += v0.y + v1.y + v2.y + v3.y;
  }
  for (; i < e; ++i) {
    int c = col[i];
    float2 v = *(const float2*)(x + (size_t)c * HIDDEN + off);
    acc.x += v.x;
    acc.y += v.y;
  }
  *(float2*)(out + (size_t)wid * HIDDEN + off) = acc;
}

// ---------------------------------------------------------------------------
// C[M,128] = act(A[M,128] @ W[128,128] + bias)   (act = relu if applyRelu)
// Block: 256 threads computes a 64x64 tile; micro-tile 4x4 per thread.
// ---------------------------------------------------------------------------
__global__ __launch_bounds__(256) void gemm_bias_relu_kernel(
    const float* __restrict__ A, const float* __restrict__ W,
    const float* __restrict__ bias, float* __restrict__ C, int M,
    int applyRelu) {
  __shared__ float xs[64][68];
  __shared__ float ws[64][68];
  const int t = threadIdx.x;
  const int tx = t & 15;
  const int ty = t >> 4;
  const int mBase = blockIdx.x * 64;
  const int nBase = blockIdx.y * 64;

  float acc[4][4];
#pragma unroll
  for (int i = 0; i < 4; ++i)
#pragma unroll
    for (int j = 0; j < 4; ++j) acc[i][j] = 0.f;

  for (int kt = 0; kt < HIDDEN; kt += 64) {
#pragma unroll
    for (int i = 0; i < 4; ++i) {
      int idx = t + i * 256;
      int r = idx >> 4;
      int c = (idx & 15) * 4;
      int gm = mBase + r;
      float4 xv = make_float4(0.f, 0.f, 0.f, 0.f);
      if (gm < M) xv = *(const float4*)(A + (size_t)gm * HIDDEN + kt + c);
      *(float4*)&xs[r][c] = xv;
      float4 wv = *(const float4*)(W + (size_t)(kt + r) * HIDDEN + nBase + c);
      *(float4*)&ws[r][c] = wv;
    }
    __syncthreads();

#pragma unroll
    for (int k = 0; k < 64; k += 4) {
      float aa[4][4];
      float ww[4][4];
#pragma unroll
      for (int i = 0; i < 4; ++i) {
        float4 a4 = *(const float4*)&xs[ty * 4 + i][k];
        aa[i][0] = a4.x; aa[i][1] = a4.y; aa[i][2] = a4.z; aa[i][3] = a4.w;
      }
#pragma unroll
      for (int kk = 0; kk < 4; ++kk) {
        float4 w4 = *(const float4*)&ws[k + kk][tx * 4];
        ww[kk][0] = w4.x; ww[kk][1] = w4.y; ww[kk][2] = w4.z; ww[kk][3] = w4.w;
      }
#pragma unroll
      for (int i = 0; i < 4; ++i)
#pragma unroll
        for (int kk = 0; kk < 4; ++kk)
#pragma unroll
          for (int j = 0; j < 4; ++j) acc[i][j] += aa[i][kk] * ww[kk][j];
    }
    __syncthreads();
  }

  float4 bv = *(const float4*)(bias + nBase + tx * 4);
#pragma unroll
  for (int i = 0; i < 4; ++i) {
    int gm = mBase + ty * 4 + i;
    if (gm >= M) continue;
    float4 o;
    o.x = acc[i][0] + bv.x;
    o.y = acc[i][1] + bv.y;
    o.z = acc[i][2] + bv.z;
    o.w = acc[i][3] + bv.w;
    if (applyRelu) {
      o.x = fmaxf(o.x, 0.f);
      o.y = fmaxf(o.y, 0.f);
      o.z = fmaxf(o.z, 0.f);
      o.w = fmaxf(o.w, 0.f);
    }
    *(float4*)(C + (size_t)gm * HIDDEN + nBase + tx * 4) = o;
  }
}

// ---------------------------------------------------------------------------
// out[m] = dot(h[m,:], Wr) + br   — one 64-lane wave per row, shfl reduce
// ---------------------------------------------------------------------------
__global__ __launch_bounds__(256) void readout_kernel(
    const float* __restrict__ h, const float* __restrict__ Wr,
    const float* __restrict__ br, float* __restrict__ out, int M) {
  int wid = (int)((blockIdx.x * blockDim.x + threadIdx.x) >> 6);
  int lane = threadIdx.x & 63;
  if (wid >= M) return;
  float2 hv = *(const float2*)(h + (size_t)wid * HIDDEN + lane * 2);
  float2 wv = *(const float2*)(Wr + lane * 2);
  float p = hv.x * wv.x + hv.y * wv.y;
#pragma unroll
  for (int off = 32; off; off >>= 1) p += __shfl_down(p, off);
  if (lane == 0) out[wid] = p + br[0];
}

extern "C" void kernel_launch(void* const* d_in, const int* in_sizes, int n_in,
                              void* d_out, int out_size, void* d_ws,
                              size_t ws_size, hipStream_t stream) {
  const float* x = (const float*)d_in[0];
  const int* ei = (const int*)d_in[1];
  const float* W1_0 = (const float*)d_in[2];
  const float* b1_0 = (const float*)d_in[3];
  const float* W2_0 = (const float*)d_in[4];
  const float* b2_0 = (const float*)d_in[5];
  const float* W1_1 = (const float*)d_in[6];
  const float* b1_1 = (const float*)d_in[7];
  const float* W2_1 = (const float*)d_in[8];
  const float* b2_1 = (const float*)d_in[9];
  const float* Wr = (const float*)d_in[10];
  const float* br = (const float*)d_in[11];

  const int M = in_sizes[0] / HIDDEN;  // 50000 nodes
  const int E = in_sizes[1] / 2;       // 800000 edges
  const int* src = ei;
  const int* dst = ei + E;

  // workspace layout
  float* A = (float*)d_ws;                   // [M,128]
  float* B = A + (size_t)M * HIDDEN;         // [M,128]
  int* deg = (int*)(B + (size_t)M * HIDDEN); // [M]
  int* rowptr = deg + M;                     // [M+1]
  int* cursor = rowptr + M + 1;              // [M]
  int* col = cursor + M;                     // [E]
  int* partial = col + E;                    // [256]
  int* blockOff = partial + 256;             // [256]

  dim3 gemmGrid((M + 63) / 64, HIDDEN / 64);
  const int aggBlocks = (int)(((size_t)M * 64 + 255) / 256);
  const int scanBlocks = (M + SCAN_CHUNK - 1) / SCAN_CHUNK;  // 196 <= 256
  float* out = (float*)d_out;

  // ---- build CSR (dst -> list of src), reused by both layers
  hipMemsetAsync(deg, 0, (size_t)M * sizeof(int), stream);
  hist_kernel<<<(E + 255) / 256, 256, 0, stream>>>(dst, deg, E);
  scan_partial_kernel<<<scanBlocks, 256, 0, stream>>>(deg, partial, M);
  scan_offsets_kernel<<<1, 256, 0, stream>>>(partial, blockOff, scanBlocks);
  scan_final_kernel<<<scanBlocks, 256, 0, stream>>>(deg, blockOff, rowptr,
                                                    cursor, M);
  fill_kernel<<<(E + 255) / 256, 256, 0, stream>>>(src, dst, cursor, col, E);

  // ---- layer 0
  aggregate_kernel<<<aggBlocks, 256, 0, stream>>>(x, rowptr, col, A, M);
  gemm_bias_relu_kernel<<<gemmGrid, 256, 0, stream>>>(A, W1_0, b1_0, B, M, 1);
  gemm_bias_relu_kernel<<<gemmGrid, 256, 0, stream>>>(B, W2_0, b2_0, A, M, 1);

  // ---- layer 1
  aggregate_kernel<<<aggBlocks, 256, 0, stream>>>(A, rowptr, col, B, M);
  gemm_bias_relu_kernel<<<gemmGrid, 256, 0, stream>>>(B, W1_1, b1_1, A, M, 1);
  gemm_bias_relu_kernel<<<gemmGrid, 256, 0, stream>>>(A, W2_1, b2_1, B, M, 1);

  // ---- readout
  readout_kernel<<<(M + 3) / 4, 256, 0, stream>>>(B, Wr, br, out, M);
}

// Round 4
// 406.277 us; speedup vs baseline: 7.1791x; 1.0365x over previous
//
#include <hip/hip_runtime.h>

#define HIDDEN 128
#define SCAN_CHUNK 256

// ---------------------------------------------------------------------------
// CSR build step 1: degree histogram over dst
// ---------------------------------------------------------------------------
__global__ __launch_bounds__(256) void hist_kernel(const int* __restrict__ dst,
                                                   int* __restrict__ deg, int E) {
  int e = blockIdx.x * blockDim.x + threadIdx.x;
  if (e < E) atomicAdd(&deg[dst[e]], 1);
}

// ---------------------------------------------------------------------------
// CSR scan phase A: per-block chunk sums (chunk = 256 elements, 1/thread)
// ---------------------------------------------------------------------------
__global__ __launch_bounds__(256) void scan_partial_kernel(
    const int* __restrict__ deg, int* __restrict__ partial, int N) {
  __shared__ int red[256];
  const int t = threadIdx.x;
  const int idx = blockIdx.x * SCAN_CHUNK + t;
  red[t] = (idx < N) ? deg[idx] : 0;
  __syncthreads();
#pragma unroll
  for (int off = 128; off; off >>= 1) {
    if (t < off) red[t] += red[t + off];
    __syncthreads();
  }
  if (t == 0) partial[blockIdx.x] = red[0];
}

// ---------------------------------------------------------------------------
// CSR scan phase B: one block scans the (<=256) block partials -> exclusive
// block offsets.
// ---------------------------------------------------------------------------
__global__ __launch_bounds__(256) void scan_offsets_kernel(
    const int* __restrict__ partial, int* __restrict__ blockOff, int nBlocks) {
  __shared__ int sums[256];
  const int t = threadIdx.x;
  const int p = (t < nBlocks) ? partial[t] : 0;
  sums[t] = p;
  __syncthreads();
#pragma unroll
  for (int off = 1; off < 256; off <<= 1) {
    int v = (t >= off) ? sums[t - off] : 0;
    __syncthreads();
    sums[t] += v;
    __syncthreads();
  }
  blockOff[t] = sums[t] - p;  // exclusive
}

// ---------------------------------------------------------------------------
// CSR scan phase C: per-block exclusive scan of its chunk + block offset;
// writes rowptr AND cursor.
// ---------------------------------------------------------------------------
__global__ __launch_bounds__(256) void scan_final_kernel(
    const int* __restrict__ deg, const int* __restrict__ blockOff,
    int* __restrict__ rowptr, int* __restrict__ cursor, int N) {
  __shared__ int sh[256];
  const int t = threadIdx.x;
  const int idx = blockIdx.x * SCAN_CHUNK + t;
  const int v = (idx < N) ? deg[idx] : 0;
  sh[t] = v;
  __syncthreads();
#pragma unroll
  for (int off = 1; off < 256; off <<= 1) {
    int u = (t >= off) ? sh[t - off] : 0;
    __syncthreads();
    sh[t] += u;
    __syncthreads();
  }
  const int excl = sh[t] - v + blockOff[blockIdx.x];
  if (idx < N) {
    rowptr[idx] = excl;
    cursor[idx] = excl;
    if (idx == N - 1) rowptr[N] = excl + v;
  }
}

// ---------------------------------------------------------------------------
// CSR build step 3: fill column (src) lists using per-node cursors
// ---------------------------------------------------------------------------
__global__ __launch_bounds__(256) void fill_kernel(const int* __restrict__ src,
                                                   const int* __restrict__ dst,
                                                   int* __restrict__ cursor,
                                                   int* __restrict__ col, int E) {
  int e = blockIdx.x * blockDim.x + threadIdx.x;
  if (e >= E) return;
  int pos = atomicAdd(&cursor[dst[e]], 1);
  col[pos] = src[e];
}

// ---------------------------------------------------------------------------
// Aggregation as GATHER: out[i,:] = x[i,:] + sum_{e} x[col[e],:]
// One 64-lane wave per node; each lane owns a float2 column slice.
// Beyond-L2 BW bound (~3.6 TB/s, R3 profile) — structure kept.
// ---------------------------------------------------------------------------
__global__ __launch_bounds__(256) void aggregate_kernel(
    const float* __restrict__ x, const int* __restrict__ rowptr,
    const int* __restrict__ col, float* __restrict__ out, int N) {
  int wid = (int)((blockIdx.x * (size_t)blockDim.x + threadIdx.x) >> 6);
  int lane = threadIdx.x & 63;
  if (wid >= N) return;
  const int s = rowptr[wid];
  const int e = rowptr[wid + 1];
  const int off = lane * 2;
  float2 acc = *(const float2*)(x + (size_t)wid * HIDDEN + off);
  int i = s;
  for (; i + 3 < e; i += 4) {
    int c0 = col[i], c1 = col[i + 1], c2 = col[i + 2], c3 = col[i + 3];
    float2 v0 = *(const float2*)(x + (size_t)c0 * HIDDEN + off);
    float2 v1 = *(const float2*)(x + (size_t)c1 * HIDDEN + off);
    float2 v2 = *(const float2*)(x + (size_t)c2 * HIDDEN + off);
    float2 v3 = *(const float2*)(x + (size_t)c3 * HIDDEN + off);
    acc.x += v0.x + v1.x + v2.x + v3.x;
    acc.y += v0.y + v1.y + v2.y + v3.y;
  }
  for (; i < e; ++i) {
    int c = col[i];
    float2 v = *(const float2*)(x + (size_t)c * HIDDEN + off);
    acc.x += v.x;
    acc.y += v.y;
  }
  *(float2*)(out + (size_t)wid * HIDDEN + off) = acc;
}

// ---------------------------------------------------------------------------
// One MLP GEMM pass over K=128: acc[4][4] += xs-tile @ W, W staged in LDS in
// 64-row chunks. Leading __syncthreads protects xs/ws reuse.
// ---------------------------------------------------------------------------
__device__ __forceinline__ void mlp_pass(const float (*xs)[132],
                                         float (*ws)[132],
                                         const float* __restrict__ W, int tx,
                                         int ty, int t, float acc[4][4]) {
  for (int kt = 0; kt < HIDDEN; kt += 64) {
    __syncthreads();
#pragma unroll
    for (int i = 0; i < 8; ++i) {
      int idx = t + i * 256;     // 0..2047
      int r = idx >> 5;          // 0..63
      int c = (idx & 31) * 4;    // 0..124
      *(float4*)&ws[r][c] = *(const float4*)(W + (size_t)(kt + r) * HIDDEN + c);
    }
    __syncthreads();
#pragma unroll
    for (int k = 0; k < 64; k += 4) {
      float av[4][4], wv[4][4];
#pragma unroll
      for (int i = 0; i < 4; ++i) {
        float4 a4 = *(const float4*)&xs[ty * 4 + i][kt + k];
        av[i][0] = a4.x; av[i][1] = a4.y; av[i][2] = a4.z; av[i][3] = a4.w;
      }
#pragma unroll
      for (int kk = 0; kk < 4; ++kk) {
        float4 w4 = *(const float4*)&ws[k + kk][tx * 4];
        wv[kk][0] = w4.x; wv[kk][1] = w4.y; wv[kk][2] = w4.z; wv[kk][3] = w4.w;
      }
#pragma unroll
      for (int i = 0; i < 4; ++i)
#pragma unroll
        for (int kk = 0; kk < 4; ++kk)
#pragma unroll
          for (int j = 0; j < 4; ++j) acc[i][j] += av[i][kk] * wv[kk][j];
    }
  }
}

// ---------------------------------------------------------------------------
// Fused MLP: h2 = relu( relu(A@W1+b1) @ W2 + b2 ) for a 32-row tile.
// h1 lives only in LDS. If doReadout: out[m] = h2[m,:]·Wr + br (h2 never hits
// global); else h2 -> Cout.
// Thread grid 32x8: tx owns 4 cols (n=tx*4), ty owns 4 rows (m=ty*4+i).
// LDS 50.7 KB -> 3 blocks/CU.
// ---------------------------------------------------------------------------
__global__ __launch_bounds__(256) void mlp_kernel(
    const float* __restrict__ A, const float* __restrict__ W1,
    const float* __restrict__ b1, const float* __restrict__ W2,
    const float* __restrict__ b2, float* __restrict__ Cout,
    const float* __restrict__ Wr, const float* __restrict__ br,
    float* __restrict__ outv, int M, int doReadout) {
  __shared__ float xs[32][132];
  __shared__ float ws[64][132];
  const int t = threadIdx.x;
  const int tx = t & 31;
  const int ty = t >> 5;
  const int mBase = blockIdx.x * 32;

  // stage A tile (32 x 128), zero-pad rows past M
#pragma unroll
  for (int i = 0; i < 4; ++i) {
    int idx = t + i * 256;     // 0..1023
    int r = idx >> 5;          // 0..31
    int c = (idx & 31) * 4;
    int gm = mBase + r;
    float4 v = make_float4(0.f, 0.f, 0.f, 0.f);
    if (gm < M) v = *(const float4*)(A + (size_t)gm * HIDDEN + c);
    *(float4*)&xs[r][c] = v;
  }

  float acc[4][4];
#pragma unroll
  for (int i = 0; i < 4; ++i)
#pragma unroll
    for (int j = 0; j < 4; ++j) acc[i][j] = 0.f;

  // MLP1
  mlp_pass(xs, ws, W1, tx, ty, t, acc);

  __syncthreads();  // all reads of xs done before h1 overwrite
  float4 b1v = *(const float4*)(b1 + tx * 4);
#pragma unroll
  for (int i = 0; i < 4; ++i) {
    float4 h;
    h.x = fmaxf(acc[i][0] + b1v.x, 0.f);
    h.y = fmaxf(acc[i][1] + b1v.y, 0.f);
    h.z = fmaxf(acc[i][2] + b1v.z, 0.f);
    h.w = fmaxf(acc[i][3] + b1v.w, 0.f);
    *(float4*)&xs[ty * 4 + i][tx * 4] = h;
    acc[i][0] = acc[i][1] = acc[i][2] = acc[i][3] = 0.f;
  }
  // (mlp_pass's leading barrier makes h1 visible before compute)

  // MLP2
  mlp_pass(xs, ws, W2, tx, ty, t, acc);

  float4 b2v = *(const float4*)(b2 + tx * 4);
  if (!doReadout) {
#pragma unroll
    for (int i = 0; i < 4; ++i) {
      int gm = mBase + ty * 4 + i;
      if (gm >= M) continue;
      float4 o;
      o.x = fmaxf(acc[i][0] + b2v.x, 0.f);
      o.y = fmaxf(acc[i][1] + b2v.y, 0.f);
      o.z = fmaxf(acc[i][2] + b2v.z, 0.f);
      o.w = fmaxf(acc[i][3] + b2v.w, 0.f);
      *(float4*)(Cout + (size_t)gm * HIDDEN + tx * 4) = o;
    }
  } else {
    float4 wr = *(const float4*)(Wr + tx * 4);
    float brv = br[0];
#pragma unroll
    for (int i = 0; i < 4; ++i) {
      float h0 = fmaxf(acc[i][0] + b2v.x, 0.f);
      float h1 = fmaxf(acc[i][1] + b2v.y, 0.f);
      float h2 = fmaxf(acc[i][2] + b2v.z, 0.f);
      float h3 = fmaxf(acc[i][3] + b2v.w, 0.f);
      float p = h0 * wr.x + h1 * wr.y + h2 * wr.z + h3 * wr.w;
      // reduce across the 32 tx lanes (xor<32 stays within each half-wave)
      p += __shfl_xor(p, 16);
      p += __shfl_xor(p, 8);
      p += __shfl_xor(p, 4);
      p += __shfl_xor(p, 2);
      p += __shfl_xor(p, 1);
      int gm = mBase + ty * 4 + i;
      if (tx == 0 && gm < M) outv[gm] = p + brv;
    }
  }
}

extern "C" void kernel_launch(void* const* d_in, const int* in_sizes, int n_in,
                              void* d_out, int out_size, void* d_ws,
                              size_t ws_size, hipStream_t stream) {
  const float* x = (const float*)d_in[0];
  const int* ei = (const int*)d_in[1];
  const float* W1_0 = (const float*)d_in[2];
  const float* b1_0 = (const float*)d_in[3];
  const float* W2_0 = (const float*)d_in[4];
  const float* b2_0 = (const float*)d_in[5];
  const float* W1_1 = (const float*)d_in[6];
  const float* b1_1 = (const float*)d_in[7];
  const float* W2_1 = (const float*)d_in[8];
  const float* b2_1 = (const float*)d_in[9];
  const float* Wr = (const float*)d_in[10];
  const float* br = (const float*)d_in[11];

  const int M = in_sizes[0] / HIDDEN;  // 50000 nodes
  const int E = in_sizes[1] / 2;       // 800000 edges
  const int* src = ei;
  const int* dst = ei + E;

  // workspace layout
  float* A = (float*)d_ws;                   // [M,128]
  float* B = A + (size_t)M * HIDDEN;         // [M,128]
  int* deg = (int*)(B + (size_t)M * HIDDEN); // [M]
  int* rowptr = deg + M;                     // [M+1]
  int* cursor = rowptr + M + 1;              // [M]
  int* col = cursor + M;                     // [E]
  int* partial = col + E;                    // [256]
  int* blockOff = partial + 256;             // [256]

  const int aggBlocks = (int)(((size_t)M * 64 + 255) / 256);
  const int scanBlocks = (M + SCAN_CHUNK - 1) / SCAN_CHUNK;
  const int mlpBlocks = (M + 31) / 32;
  float* out = (float*)d_out;

  // ---- build CSR (dst -> list of src), reused by both layers
  hipMemsetAsync(deg, 0, (size_t)M * sizeof(int), stream);
  hist_kernel<<<(E + 255) / 256, 256, 0, stream>>>(dst, deg, E);
  scan_partial_kernel<<<scanBlocks, 256, 0, stream>>>(deg, partial, M);
  scan_offsets_kernel<<<1, 256, 0, stream>>>(partial, blockOff, scanBlocks);
  scan_final_kernel<<<scanBlocks, 256, 0, stream>>>(deg, blockOff, rowptr,
                                                    cursor, M);
  fill_kernel<<<(E + 255) / 256, 256, 0, stream>>>(src, dst, cursor, col, E);

  // ---- layer 0: agg -> fused MLP -> B
  aggregate_kernel<<<aggBlocks, 256, 0, stream>>>(x, rowptr, col, A, M);
  mlp_kernel<<<mlpBlocks, 256, 0, stream>>>(A, W1_0, b1_0, W2_0, b2_0, B,
                                            nullptr, nullptr, nullptr, M, 0);

  // ---- layer 1: agg -> fused MLP + readout -> out
  aggregate_kernel<<<aggBlocks, 256, 0, stream>>>(B, rowptr, col, A, M);
  mlp_kernel<<<mlpBlocks, 256, 0, stream>>>(A, W1_1, b1_1, W2_1, b2_1, nullptr,
                                            Wr, br, out, M, 1);
}